// Round 6
// baseline (198.928 us; speedup 1.0000x reference)
//
#include <hip/hip_runtime.h>

#define H 1024
#define HH (H * H)          // 1048576 per channel plane
#define CHW (3 * HH)        // 3145728 per image
#define NB 256
#define HIST_BLOCKS 784

typedef float nfloat4 __attribute__((ext_vector_type(4)));   // native vec for nontemporal builtin

__device__ __forceinline__ float clamp01(float x) { return fminf(fmaxf(x, 0.0f), 1.0f); }

// bin of a value already divided by 255 (v01 = masked_value/255, mask in {0,1})
// (int)(v01*255) is bit-exact vs reference's (int)(clamp01(..)*255*mask).
__device__ __forceinline__ unsigned int bin8(float v01) {
    int b = (int)(v01 * 255.0f);
    return (unsigned int)min(max(b, 0), NB - 1);
}

__device__ __forceinline__ void nt_store4(float4 v, float4* p) {
    nfloat4 nv; nv.x = v.x; nv.y = v.y; nv.z = v.z; nv.w = v.w;
    __builtin_nontemporal_store(nv, reinterpret_cast<nfloat4*>(p));
}

// ---------------------------------------------------------------------------
// Stage 1: elementwise masking + packed per-pixel bin triples.
// Block 0 additionally zeroes ghist[1536] + done-counter + loss (consumed by
// later kernels; kernel-boundary ordering guarantees visibility).
// out0/out1 use nontemporal stores (never re-read by our kernels).
// ---------------------------------------------------------------------------
__global__ void k_elementwise(const float4* __restrict__ inp,
                              const float4* __restrict__ tar,
                              const float4* __restrict__ rfp,
                              const float4* __restrict__ msrc,
                              const float4* __restrict__ mtar,
                              float4* __restrict__ out0, float4* __restrict__ out1,
                              float4* __restrict__ out2, float4* __restrict__ out3,
                              uint4* __restrict__ pk_dst, uint4* __restrict__ pk_ref,
                              unsigned int* __restrict__ gz, float* __restrict__ loss)
{
    if (blockIdx.x == 0) {
        for (int i = threadIdx.x; i < 1537; i += blockDim.x) gz[i] = 0u;   // ghist + counter
        if (threadIdx.x == 0) *loss = 0.0f;
    }
    int p = blockIdx.x * blockDim.x + threadIdx.x;
    if (p >= HH / 4) return;
    float4 ms4 = msrc[p], mt4 = mtar[p];
    // true division: 255.0f/255.0f == 1.0f exactly
    float msx = ms4.x / 255.0f, msy = ms4.y / 255.0f, msz = ms4.z / 255.0f, msw = ms4.w / 255.0f;
    float mtx = mt4.x / 255.0f, mty = mt4.y / 255.0f, mtz = mt4.z / 255.0f, mtw = mt4.w / 255.0f;
    unsigned int bd0 = 0, bd1 = 0, bd2 = 0, bd3 = 0;
    unsigned int br0 = 0, br1 = 0, br2 = 0, br3 = 0;
#pragma unroll
    for (int c = 0; c < 3; ++c) {
        int q = c * (HH / 4) + p;
        float4 t = tar[q], r = rfp[q], iv = inp[q];
        float4 o0, o1, o2;
        o0.x = clamp01((t.x + 1.0f) * 0.5f) * mtx;
        o0.y = clamp01((t.y + 1.0f) * 0.5f) * mty;
        o0.z = clamp01((t.z + 1.0f) * 0.5f) * mtz;
        o0.w = clamp01((t.w + 1.0f) * 0.5f) * mtw;
        o1.x = clamp01((r.x + 1.0f) * 0.5f) * msx;
        o1.y = clamp01((r.y + 1.0f) * 0.5f) * msy;
        o1.z = clamp01((r.z + 1.0f) * 0.5f) * msz;
        o1.w = clamp01((r.w + 1.0f) * 0.5f) * msw;
        o2.x = clamp01(iv.x) * msx;
        o2.y = clamp01(iv.y) * msy;
        o2.z = clamp01(iv.z) * msz;
        o2.w = clamp01(iv.w) * msw;
        nt_store4(o0, &out0[q]);
        nt_store4(o1, &out1[q]);
        out3[q] = o1;           // re-read by k_loss: keep cached
        out2[q] = o2;           // re-read by k_loss: keep cached
        int sh = 8 * c;
        bd0 |= bin8(o1.x) << sh;  bd1 |= bin8(o1.y) << sh;
        bd2 |= bin8(o1.z) << sh;  bd3 |= bin8(o1.w) << sh;
        br0 |= bin8(o0.x) << sh;  br1 |= bin8(o0.y) << sh;
        br2 |= bin8(o0.z) << sh;  br3 |= bin8(o0.w) << sh;
    }
    pk_dst[p] = make_uint4(bd0, bd1, bd2, bd3);
    pk_ref[p] = make_uint4(br0, br1, br2, br3);
}

// ---------------------------------------------------------------------------
// Stage 2+3 fused: histograms from packed bins; LAST block (device-scope
// done-counter) computes cdfs + transfer table.
// CDF: atomic reads of 4 bins/lane -> register scan of 4 -> wave shfl_up
// scan (integer, bit-exact) -> float divide by total. Table: 8-step binary
// search on monotone cdf_ref, identical comparisons to reference first-hit.
// Table stored PRE-DIVIDED by 255 (the reference's single fp divide).
// ---------------------------------------------------------------------------
__global__ void k_hist(const unsigned int* __restrict__ pk_dst,
                       const unsigned int* __restrict__ pk_ref,
                       const int* __restrict__ i0, const int* __restrict__ i1,
                       const int* __restrict__ i2, const int* __restrict__ i3,
                       unsigned int* __restrict__ ghist, unsigned int* __restrict__ counter,
                       float* __restrict__ table, int n)
{
    __shared__ unsigned int h[2 * 3 * NB];
    __shared__ float cdf[6][NB];
    __shared__ bool amLast;
    for (int i = threadIdx.x; i < 2 * 3 * NB; i += blockDim.x) h[i] = 0u;
    __syncthreads();

    for (int k = blockIdx.x * blockDim.x + threadIdx.x; k < n; k += gridDim.x * blockDim.x) {
        int pd = i0[k] * H + i1[k];
        int pr = i2[k] * H + i3[k];
        unsigned int a = pk_dst[pd];
        unsigned int b = pk_ref[pr];
        atomicAdd(&h[        (a       & 255u)], 1u);
        atomicAdd(&h[  NB + ((a >> 8) & 255u)], 1u);
        atomicAdd(&h[2*NB + ((a >>16) & 255u)], 1u);
        atomicAdd(&h[3*NB + ( b       & 255u)], 1u);
        atomicAdd(&h[4*NB + ((b >> 8) & 255u)], 1u);
        atomicAdd(&h[5*NB + ((b >>16) & 255u)], 1u);
    }
    __syncthreads();
    for (int i = threadIdx.x; i < 2 * 3 * NB; i += blockDim.x) {
        unsigned int v = h[i];
        if (v) atomicAdd(&ghist[i], v);
    }

    // completion count; last block computes the tables
    if (threadIdx.x == 0) {
        __threadfence();
        unsigned int old = atomicAdd(counter, 1u);
        amLast = (old == (unsigned int)(gridDim.x - 1));
    }
    __syncthreads();
    if (!amLast) return;

    int t = threadIdx.x;
    if (t < 384) {
        int wave = t >> 6, lane = t & 63;
        int base = wave * NB + lane * 4;
        // device-scope atomic reads: acquire-safe vs other XCDs' atomicAdds
        unsigned int v0 = atomicAdd(&ghist[base + 0], 0u);
        unsigned int v1 = atomicAdd(&ghist[base + 1], 0u);
        unsigned int v2 = atomicAdd(&ghist[base + 2], 0u);
        unsigned int v3 = atomicAdd(&ghist[base + 3], 0u);
        unsigned int s0 = v0, s1 = s0 + v1, s2 = s1 + v2, s3 = s2 + v3;
        unsigned int scan = s3;
#pragma unroll
        for (int off = 1; off < 64; off <<= 1) {
            unsigned int u = (unsigned int)__shfl_up((int)scan, off, 64);
            if (lane >= off) scan += u;
        }
        unsigned int prefix = scan - s3;
        unsigned int total  = (unsigned int)__shfl((int)scan, 63, 64);
        float ft = (float)total;
        cdf[wave][lane * 4 + 0] = (float)(prefix + s0) / ft;
        cdf[wave][lane * 4 + 1] = (float)(prefix + s1) / ft;
        cdf[wave][lane * 4 + 2] = (float)(prefix + s2) / ft;
        cdf[wave][lane * 4 + 3] = (float)(prefix + s3) / ft;
    }
    __syncthreads();
    if (t < NB) {
#pragma unroll
        for (int c = 0; c < 3; ++c) {
            float r = cdf[c][t];
            const float* cr = cdf[3 + c];
            int lo = 1, hi = NB - 1;
#pragma unroll
            for (int it = 0; it < 8; ++it) {
                int mid = (lo + hi) >> 1;
                if (cr[mid] >= r) hi = mid; else lo = mid + 1;
            }
            int jstar = lo - 1;
            int tab = (jstar == 0 && cr[0] > r) ? t : (jstar + 1);
            if (t == NB - 1) tab = NB - 1;
            table[c * NB + t] = (float)tab / 255.0f;
        }
    }
}

// ---------------------------------------------------------------------------
// Stage 4: scatter table-mapped values into out3 using packed bins.
// Table staged in LDS. Duplicate pixels write identical values.
// ---------------------------------------------------------------------------
__global__ void k_scatter(const unsigned int* __restrict__ pk_dst,
                          const int* __restrict__ i0, const int* __restrict__ i1,
                          const float* __restrict__ table, float* __restrict__ out3, int n)
{
    __shared__ float tl[3 * NB];
    for (int i = threadIdx.x; i < 3 * NB; i += blockDim.x) tl[i] = table[i];
    __syncthreads();
    int k = blockIdx.x * blockDim.x + threadIdx.x;
    if (k >= n) return;
    int pd = i0[k] * H + i1[k];
    unsigned int a = pk_dst[pd];
    out3[         pd] = tl[        (a       & 255u)];
    out3[HH     + pd] = tl[  NB + ((a >> 8) & 255u)];
    out3[2 * HH + pd] = tl[2*NB + ((a >>16) & 255u)];
}

// ---------------------------------------------------------------------------
// Stage 5: loss = mean |out2 - out3| over 3*H*H elements.
// ---------------------------------------------------------------------------
__global__ void k_loss(const float4* __restrict__ a, const float4* __restrict__ b,
                       float* __restrict__ loss)
{
    float s = 0.0f;
    int n4 = CHW / 4;
    for (int i = blockIdx.x * blockDim.x + threadIdx.x; i < n4; i += gridDim.x * blockDim.x) {
        float4 x = a[i], y = b[i];
        s += fabsf(x.x - y.x) + fabsf(x.y - y.y) + fabsf(x.z - y.z) + fabsf(x.w - y.w);
    }
#pragma unroll
    for (int off = 32; off > 0; off >>= 1) s += __shfl_down(s, off);
    __shared__ float ws[4];
    int lane = threadIdx.x & 63, w = threadIdx.x >> 6;
    if (lane == 0) ws[w] = s;
    __syncthreads();
    if (threadIdx.x == 0) {
        float tsum = ws[0] + ws[1] + ws[2] + ws[3];
        atomicAdd(loss, tsum * (1.0f / (float)CHW));
    }
}

extern "C" void kernel_launch(void* const* d_in, const int* in_sizes, int n_in,
                              void* d_out, int out_size, void* d_ws, size_t ws_size,
                              hipStream_t stream)
{
    const float* inp  = (const float*)d_in[0];
    const float* tar  = (const float*)d_in[1];
    const float* rfp  = (const float*)d_in[2];
    const float* msrc = (const float*)d_in[3];
    const float* mtar = (const float*)d_in[4];
    // d_in[5] = target_data_eye (unused by the reference computation)
    const int* i0 = (const int*)d_in[6];
    const int* i1 = (const int*)d_in[7];
    const int* i2 = (const int*)d_in[8];
    const int* i3 = (const int*)d_in[9];
    int n = in_sizes[6];

    float* out0 = (float*)d_out;
    float* out1 = out0 + CHW;
    float* out2 = out1 + CHW;
    float* out3 = out2 + CHW;
    float* loss = out3 + CHW;

    // workspace layout
    unsigned int* ghist   = (unsigned int*)d_ws;                     // [0,6144): 1536 u32
    unsigned int* counter = ghist + 1536;                            // [6144,6148): 1 u32
    float*        table   = (float*)((char*)d_ws + 8192);            // 768 f32
    unsigned int* pk_dst  = (unsigned int*)((char*)d_ws + 16384);    // HH u32 (4 MB)
    unsigned int* pk_ref  = pk_dst + HH;                             // HH u32 (4 MB)

    k_elementwise<<<(HH / 4 + 255) / 256, 256, 0, stream>>>(
        (const float4*)inp, (const float4*)tar, (const float4*)rfp,
        (const float4*)msrc, (const float4*)mtar,
        (float4*)out0, (float4*)out1, (float4*)out2, (float4*)out3,
        (uint4*)pk_dst, (uint4*)pk_ref, ghist, loss);

    k_hist<<<HIST_BLOCKS, 512, 0, stream>>>(pk_dst, pk_ref, i0, i1, i2, i3,
                                            ghist, counter, table, n);

    k_scatter<<<(n + 255) / 256, 256, 0, stream>>>(pk_dst, i0, i1, table, out3, n);

    k_loss<<<768, 256, 0, stream>>>((const float4*)out2, (const float4*)out3, loss);
}